// Round 9
// baseline (289.222 us; speedup 1.0000x reference)
//
#include <hip/hip_runtime.h>
#include <stdint.h>

typedef float f32x4 __attribute__((ext_vector_type(4)));
typedef __bf16 bf16x8 __attribute__((ext_vector_type(8)));
typedef unsigned short ushort_t;
typedef ushort_t ushortx8 __attribute__((ext_vector_type(8)));
typedef ushort_t ushortx4 __attribute__((ext_vector_type(4)));

#define DEV static __device__ __forceinline__

DEV ushort_t f2bf(float f) {
  union { float f; uint32_t u; } v; v.f = f;
  uint32_t u = v.u;
  return (ushort_t)((u + 0x7FFFu + ((u >> 16) & 1u)) >> 16);
}

DEV uint32_t pkbf(float a, float b) {
  __bf16 x = (__bf16)a, y = (__bf16)b;
  return (uint32_t)__builtin_bit_cast(unsigned short, x) |
         ((uint32_t)__builtin_bit_cast(unsigned short, y) << 16);
}

DEV void cp16(const void* g, void* l) {
  __builtin_amdgcn_global_load_lds((const __attribute__((address_space(1))) unsigned int*)g,
                                   (__attribute__((address_space(3))) unsigned int*)l,
                                   16, 0, 0);
}

DEV f32x4 mfma16(bf16x8 a, bf16x8 b, f32x4 c) {
  return __builtin_amdgcn_mfma_f32_16x16x32_bf16(a, b, c, 0, 0, 0);
}

// ------------- merged prep: cvt x (blocks 0..4095), 4 weight transposes -----
__global__ __launch_bounds__(256) void k_prep(
    const float* __restrict__ x, ushort_t* __restrict__ xb,
    const float* __restrict__ wq, const float* __restrict__ wk,
    const float* __restrict__ wv, const float* __restrict__ wo,
    ushort_t* __restrict__ wqkvT, ushort_t* __restrict__ woT) {
  __shared__ float tile[32][33];
  int b = blockIdx.x;
  if (b < 4096) {
    size_t idx = ((size_t)b * 256 + threadIdx.x) * 8;
    const float4* src = (const float4*)(x + idx);
    float4 a = src[0], c = src[1];
    ushortx8 o;
    o[0] = f2bf(a.x); o[1] = f2bf(a.y); o[2] = f2bf(a.z); o[3] = f2bf(a.w);
    o[4] = f2bf(c.x); o[5] = f2bf(c.y); o[6] = f2bf(c.z); o[7] = f2bf(c.w);
    *(ushortx8*)(xb + idx) = o;
  } else {
    int t = b - 4096;
    int which = t >> 10;  // 0=wq 1=wk 2=wv 3=wo
    const float* src = (which == 0) ? wq : (which == 1) ? wk : (which == 2) ? wv : wo;
    ushort_t* dst = (which == 0) ? wqkvT
                    : (which == 1) ? wqkvT + 1024 * 1024
                    : (which == 2) ? wqkvT + 2 * 1024 * 1024
                                   : woT;
    int tt = t & 1023;
    int c0 = (tt & 31) * 32, r0 = (tt >> 5) * 32;
    int tx = threadIdx.x & 31, ty = threadIdx.x >> 5;
#pragma unroll
    for (int i = ty; i < 32; i += 8)
      tile[i][tx] = src[(size_t)(r0 + i) * 1024 + c0 + tx];
    __syncthreads();
#pragma unroll
    for (int i = ty; i < 32; i += 8)
      dst[(size_t)(c0 + i) * 1024 + r0 + tx] = f2bf(tile[tx][i]);
  }
}

// ------- unified GEMM: 128x256 tile, BK=64, 4-phase counted-vmcnt ----------
// (unchanged from R6)
template <int MODE>
__global__ __launch_bounds__(512, 1) void k_gemm2(
    const ushort_t* __restrict__ A, const ushort_t* __restrict__ Bt,
    const float* __restrict__ b0, const float* __restrict__ b1,
    const float* __restrict__ b2, ushort_t* __restrict__ qw,
    ushort_t* __restrict__ kw, ushort_t* __restrict__ vtw,
    float* __restrict__ outf) {
  extern __shared__ ushort_t lds[];
  ushort_t* As2 = lds;             // [2][128*64] = 32 KiB
  ushort_t* Bs2 = lds + 2 * 8192;  // [2][256*64] = 64 KiB
  const int K = 1024, NT = 16;
  int tid = threadIdx.x;
  int w = tid >> 6, lane = tid & 63, l16 = lane & 15, lg = lane >> 4;
  int wr = w >> 2, wc = w & 3;
  int m0 = blockIdx.x * 128, n0 = blockIdx.y * 256;

  const ushort_t* Asrc = A + (size_t)(m0 + (tid >> 3)) * K +
                         (size_t)(((tid & 7) ^ ((tid >> 3) & 7)) * 8);
  const ushort_t* Bsrc = Bt + (size_t)(n0 + (tid >> 3)) * K +
                         (size_t)(((tid & 7) ^ ((tid >> 3) & 7)) * 8);

  f32x4 acc[4][4] = {};
  bf16x8 a[2][2], b[4][2];
  const int aRow = wr * 64 + l16, bRow = wc * 64 + l16, rsw = l16 & 7;

  // prologue: A0 (2 sweeps) + B0 (4 sweeps) + B1 s0,s1; wait tile0 (leave 2)
  cp16(Asrc, As2 + w * 512);
  cp16(Asrc + (size_t)64 * K, As2 + 4096 + w * 512);
#pragma unroll
  for (int s = 0; s < 4; ++s)
    cp16(Bsrc + (size_t)s * 64 * K, Bs2 + s * 4096 + w * 512);
  cp16(Bsrc + 64, Bs2 + 16384 + w * 512);
  cp16(Bsrc + 64 + (size_t)64 * K, Bs2 + 16384 + 4096 + w * 512);
  asm volatile("s_waitcnt vmcnt(2)" ::: "memory");
  __builtin_amdgcn_s_barrier();

  for (int t = 0; t < NT; ++t) {
    int cur = t & 1, nxt = cur ^ 1;
    ushort_t* AsC = As2 + cur * 8192;
    ushort_t* BsC = Bs2 + cur * 16384;
    int t1 = (t + 1 < NT) ? t + 1 : NT - 1;
    int t2 = (t + 2 < NT) ? t + 2 : NT - 1;
    const ushort_t* An = Asrc + (size_t)t1 * 64;
    const ushort_t* Bn = Bsrc + (size_t)t1 * 64;

    // ---- phase 1: read a0,a1 + b0,b1; stage B(t+1) s2,s3
#pragma unroll
    for (int i2 = 0; i2 < 2; ++i2)
#pragma unroll
      for (int ks = 0; ks < 2; ++ks)
        a[i2][ks] = *(const bf16x8*)&AsC[(aRow + i2 * 16) * 64 +
                                         (((ks << 2) | lg) ^ rsw) * 8];
#pragma unroll
    for (int j2 = 0; j2 < 2; ++j2)
#pragma unroll
      for (int ks = 0; ks < 2; ++ks)
        b[j2][ks] = *(const bf16x8*)&BsC[(bRow + j2 * 16) * 64 +
                                         (((ks << 2) | lg) ^ rsw) * 8];
    cp16(Bn + (size_t)2 * 64 * K, Bs2 + nxt * 16384 + 2 * 4096 + w * 512);
    cp16(Bn + (size_t)3 * 64 * K, Bs2 + nxt * 16384 + 3 * 4096 + w * 512);
    __builtin_amdgcn_s_barrier();
    asm volatile("s_waitcnt lgkmcnt(0)" ::: "memory");
    __builtin_amdgcn_s_setprio(1);
#pragma unroll
    for (int i2 = 0; i2 < 2; ++i2)
#pragma unroll
      for (int j2 = 0; j2 < 2; ++j2)
#pragma unroll
        for (int ks = 0; ks < 2; ++ks)
          acc[i2][j2] = mfma16(a[i2][ks], b[j2][ks], acc[i2][j2]);
    __builtin_amdgcn_s_setprio(0);
    __builtin_amdgcn_s_barrier();

    // ---- phase 2: read b2,b3; stage A(t+1) s0,s1
#pragma unroll
    for (int j2 = 2; j2 < 4; ++j2)
#pragma unroll
      for (int ks = 0; ks < 2; ++ks)
        b[j2][ks] = *(const bf16x8*)&BsC[(bRow + j2 * 16) * 64 +
                                         (((ks << 2) | lg) ^ rsw) * 8];
    cp16(An, As2 + nxt * 8192 + w * 512);
    cp16(An + (size_t)64 * K, As2 + nxt * 8192 + 4096 + w * 512);
    __builtin_amdgcn_s_barrier();
    asm volatile("s_waitcnt lgkmcnt(0)" ::: "memory");
    __builtin_amdgcn_s_setprio(1);
#pragma unroll
    for (int i2 = 0; i2 < 2; ++i2)
#pragma unroll
      for (int j2 = 2; j2 < 4; ++j2)
#pragma unroll
        for (int ks = 0; ks < 2; ++ks)
          acc[i2][j2] = mfma16(a[i2][ks], b[j2][ks], acc[i2][j2]);
    __builtin_amdgcn_s_setprio(0);
    __builtin_amdgcn_s_barrier();

    // ---- phase 3: read a2,a3 (overwrite a[])
#pragma unroll
    for (int i2 = 0; i2 < 2; ++i2)
#pragma unroll
      for (int ks = 0; ks < 2; ++ks)
        a[i2][ks] = *(const bf16x8*)&AsC[(aRow + (2 + i2) * 16) * 64 +
                                         (((ks << 2) | lg) ^ rsw) * 8];
    __builtin_amdgcn_s_barrier();
    asm volatile("s_waitcnt lgkmcnt(0)" ::: "memory");
    __builtin_amdgcn_s_setprio(1);
#pragma unroll
    for (int i2 = 0; i2 < 2; ++i2)
#pragma unroll
      for (int j2 = 2; j2 < 4; ++j2)
#pragma unroll
        for (int ks = 0; ks < 2; ++ks)
          acc[2 + i2][j2] = mfma16(a[i2][ks], b[j2][ks], acc[2 + i2][j2]);
    __builtin_amdgcn_s_setprio(0);
    __builtin_amdgcn_s_barrier();

    // ---- phase 4: stage B(t+2) s0,s1 into BsC (read-free since ph2);
    //      counted wait: t+1 landed, t+2's 2 loads in flight
    cp16(Bsrc + (size_t)t2 * 64, BsC + w * 512);
    cp16(Bsrc + (size_t)t2 * 64 + (size_t)64 * K, BsC + 4096 + w * 512);
    asm volatile("s_waitcnt vmcnt(2)" ::: "memory");
    __builtin_amdgcn_s_barrier();
    __builtin_amdgcn_s_setprio(1);
#pragma unroll
    for (int i2 = 0; i2 < 2; ++i2)
#pragma unroll
      for (int j2 = 0; j2 < 2; ++j2)
#pragma unroll
        for (int ks = 0; ks < 2; ++ks)
          acc[2 + i2][j2] = mfma16(a[i2][ks], b[j2][ks], acc[2 + i2][j2]);
    __builtin_amdgcn_s_setprio(0);
    __builtin_amdgcn_s_barrier();
  }

  if (MODE == 0) {
    const float QSCALE = 0.18033688011112042f;  // (1/sqrt(64)) * log2(e)
    int p = blockIdx.x >> 3;  // 0=q 1=k 2=v
    int cbase = (m0 & 1023) + wr * 64;
    if (p == 2) {
      // V: write transposed directly -> vtw[bh][dh][token]
#pragma unroll
      for (int i = 0; i < 4; ++i) {
        int oc = cbase + i * 16 + lg * 4;
        int h = oc >> 6, dh0 = oc & 63;
        float4 bb = *(const float4*)&b2[oc];
#pragma unroll
        for (int j = 0; j < 4; ++j) {
          int tok = n0 + wc * 64 + j * 16 + l16;
          int bi = tok >> 11, tk = tok & 2047;
          size_t vb = ((size_t)((bi * 16 + h) * 64 + dh0)) * 2048 + tk;
          vtw[vb] = f2bf(acc[i][j][0] + bb.x);
          vtw[vb + 2048] = f2bf(acc[i][j][1] + bb.y);
          vtw[vb + 2 * 2048] = f2bf(acc[i][j][2] + bb.z);
          vtw[vb + 3 * 2048] = f2bf(acc[i][j][3] + bb.w);
        }
      }
    } else {
      const float* bias = (p == 0) ? b0 : b1;
      ushort_t* dst = (p == 0) ? qw : kw;
      float qs = (p == 0) ? QSCALE : 1.0f;
#pragma unroll
      for (int i = 0; i < 4; ++i) {
        int oc = cbase + i * 16 + lg * 4;
        int h = oc >> 6, dh0 = oc & 63;
        float4 bb = *(const float4*)&bias[oc];
#pragma unroll
        for (int j = 0; j < 4; ++j) {
          int tok = n0 + wc * 64 + j * 16 + l16;
          size_t base =
              ((size_t)((tok >> 11) * 16 + h) * 2048 + (tok & 2047)) * 64 + dh0;
          ushortx4 pk;
          pk[0] = f2bf((acc[i][j][0] + bb.x) * qs);
          pk[1] = f2bf((acc[i][j][1] + bb.y) * qs);
          pk[2] = f2bf((acc[i][j][2] + bb.z) * qs);
          pk[3] = f2bf((acc[i][j][3] + bb.w) * qs);
          *(ushortx4*)&dst[base] = pk;
        }
      }
    }
  } else {
    // fp32 + bias
#pragma unroll
    for (int j = 0; j < 4; ++j) {
      int col = n0 + wc * 64 + j * 16 + l16;
      float bb = b0[col];
#pragma unroll
      for (int i = 0; i < 4; ++i) {
#pragma unroll
        for (int r = 0; r < 4; ++r) {
          int row = m0 + wr * 64 + i * 16 + lg * 4 + r;
          outf[(size_t)row * 1024 + col] = acc[i][j][r] + bb;
        }
      }
    }
  }
}

// ---------------- flash attention, dbuf/KV64, HALF-GRID instrumented -------
// Identical body to R6's control; grid split into two 256-block launches
// (qbase = 0 / 4) so each dispatch is ~41-45 us. Purpose: lower the top-5
// visibility threshold below the GEMM durations and reveal the true
// non-attn time split (slow GEMMs vs inter-launch gaps).
__global__ __launch_bounds__(512, 2) void k_attn(
    const ushort_t* __restrict__ qg, const ushort_t* __restrict__ kg,
    const ushort_t* __restrict__ vtg, ushort_t* __restrict__ att, int qbase) {
  __shared__ ushort_t Ks[2][64 * 64];    // dbuf [key][dh], chunk8 ^= key&7
  __shared__ ushort_t Vs[2][64 * 64];    // dbuf [dh][key], chunk8 ^= dh&7
  __shared__ ushort_t Ps[8][16 * 128];   // per-wave [q][st*64+key], chunk16 ^= q
  int tid = threadIdx.x;
  int w = tid >> 6, lane = tid & 63, l16 = lane & 15, lg = lane >> 4;
  int i = blockIdx.x;
  int bh = (i & 7) * 8 + ((i >> 3) & 7);
  int q0 = (qbase + (i >> 6)) * 256;
  const ushort_t* qh = qg + (size_t)bh * 2048 * 64;

  const ushort_t* kstage = kg + (size_t)bh * 2048 * 64 + (size_t)(tid >> 3) * 64 +
                           (size_t)(((tid & 7) ^ ((tid >> 3) & 7)) * 8);
  const ushort_t* vstage = vtg + (size_t)bh * 64 * 2048 + (size_t)(tid >> 3) * 2048 +
                           (size_t)(((tid & 7) ^ ((tid >> 3) & 7)) * 8);

  bf16x8 qf[2][2];
#pragma unroll
  for (int st = 0; st < 2; ++st)
#pragma unroll
    for (int ks = 0; ks < 2; ++ks)
      qf[st][ks] = *(const bf16x8*)(qh + (size_t)(q0 + w * 32 + st * 16 + l16) * 64 +
                                    ks * 32 + lg * 8);

  bf16x8 vone;
#pragma unroll
  for (int t = 0; t < 8; ++t) vone[t] = (__bf16)1.0f;

  f32x4 o[2][5] = {};  // [strip][dh-tile 0..3, 4 = row-sum l]

  cp16(kstage, &Ks[0][tid * 8]);
  cp16(vstage, &Vs[0][tid * 8]);
  __syncthreads();

  for (int t = 0; t < 32; ++t) {
    int cur = t & 1, nxt = cur ^ 1;
    cp16(kstage + (size_t)(t + 1) * 64 * 64, &Ks[nxt][tid * 8]);
    cp16(vstage + (size_t)(t + 1) * 64, &Vs[nxt][tid * 8]);

    f32x4 sc[2][4] = {};
    __builtin_amdgcn_s_setprio(1);
#pragma unroll
    for (int jt = 0; jt < 4; ++jt) {
      int row = jt * 16 + l16;
      bf16x8 kf0 = *(const bf16x8*)&Ks[cur][row * 64 + ((lg) ^ (l16 & 7)) * 8];
      bf16x8 kf1 = *(const bf16x8*)&Ks[cur][row * 64 + ((lg + 4) ^ (l16 & 7)) * 8];
      sc[0][jt] = mfma16(kf0, qf[0][0], sc[0][jt]);
      sc[0][jt] = mfma16(kf1, qf[0][1], sc[0][jt]);
      sc[1][jt] = mfma16(kf0, qf[1][0], sc[1][jt]);
      sc[1][jt] = mfma16(kf1, qf[1][1], sc[1][jt]);
    }
    __builtin_amdgcn_s_setprio(0);

#pragma unroll
    for (int st = 0; st < 2; ++st)
#pragma unroll
      for (int jt = 0; jt < 4; ++jt) {
        float e0 = __builtin_amdgcn_exp2f(sc[st][jt][0]);
        float e1 = __builtin_amdgcn_exp2f(sc[st][jt][1]);
        float e2 = __builtin_amdgcn_exp2f(sc[st][jt][2]);
        float e3 = __builtin_amdgcn_exp2f(sc[st][jt][3]);
        uint2 pk2;
        pk2.x = pkbf(e0, e1);
        pk2.y = pkbf(e2, e3);
        *(uint2*)&Ps[w][l16 * 128 +
                        (((st * 8 + jt * 2 + (lg >> 1)) ^ l16) * 8) +
                        (lg & 1) * 4] = pk2;
      }

    __builtin_amdgcn_s_setprio(1);
#pragma unroll
    for (int ks = 0; ks < 2; ++ks) {
      bf16x8 pf0 =
          *(const bf16x8*)&Ps[w][l16 * 128 + (((ks * 4 + lg) ^ l16) * 8)];
      bf16x8 pf1 =
          *(const bf16x8*)&Ps[w][l16 * 128 + (((8 + ks * 4 + lg) ^ l16) * 8)];
      o[0][4] = mfma16(pf0, vone, o[0][4]);
      o[1][4] = mfma16(pf1, vone, o[1][4]);
#pragma unroll
      for (int dt = 0; dt < 4; ++dt) {
        int vrow = dt * 16 + l16;
        bf16x8 vf =
            *(const bf16x8*)&Vs[cur][vrow * 64 + (((ks * 4 + lg) ^ (l16 & 7)) * 8)];
        o[0][dt] = mfma16(pf0, vf, o[0][dt]);
        o[1][dt] = mfma16(pf1, vf, o[1][dt]);
      }
    }
    __builtin_amdgcn_s_setprio(0);

    __syncthreads();
  }

  int bi = bh >> 4, h = bh & 15;
#pragma unroll
  for (int st = 0; st < 2; ++st) {
    f32x4 inv;
#pragma unroll
    for (int r = 0; r < 4; ++r) inv[r] = __builtin_amdgcn_rcpf(o[st][4][r]);
#pragma unroll
    for (int dt = 0; dt < 4; ++dt)
#pragma unroll
      for (int r = 0; r < 4; ++r) {
        int srow = q0 + w * 32 + st * 16 + lg * 4 + r;
        int col = h * 64 + dt * 16 + l16;
        att[(size_t)(bi * 2048 + srow) * 1024 + col] = f2bf(o[st][dt][r] * inv[r]);
      }
  }
}

// ---------------- host ----------------
extern "C" void kernel_launch(void* const* d_in, const int* in_sizes, int n_in,
                              void* d_out, int out_size, void* d_ws, size_t ws_size,
                              hipStream_t stream) {
  const float* x = (const float*)d_in[0];
  const float* wq = (const float*)d_in[1];
  const float* bq = (const float*)d_in[2];
  const float* wk = (const float*)d_in[3];
  const float* bk = (const float*)d_in[4];
  const float* wv = (const float*)d_in[5];
  const float* bv = (const float*)d_in[6];
  const float* wo = (const float*)d_in[7];
  const float* bo = (const float*)d_in[8];
  float* out = (float*)d_out;

  char* ws = (char*)d_ws;
  ushort_t* xb = (ushort_t*)(ws);                       // 16 MiB
  ushort_t* wqkvT = (ushort_t*)(ws + 16777216);         // 6 MiB ([3072][1024])
  ushort_t* woT = (ushort_t*)(ws + 23068672);           // 2 MiB ([1024][1024])
  ushort_t* qw = (ushort_t*)(ws + 25165824);            // 16 MiB
  ushort_t* kw = (ushort_t*)(ws + 41943040);            // 16 MiB
  ushort_t* vtw = (ushort_t*)(ws + 58720256);           // 16 MiB
  ushort_t* att = (ushort_t*)(ws + 75497472);           // 16 MiB

  k_prep<<<dim3(8192), dim3(256), 0, stream>>>(x, xb, wq, wk, wv, wo, wqkvT, woT);

  const int G2_LDS = 98304;  // 96 KiB dynamic
  hipFuncSetAttribute(reinterpret_cast<const void*>(&k_gemm2<0>),
                      hipFuncAttributeMaxDynamicSharedMemorySize, G2_LDS);
  hipFuncSetAttribute(reinterpret_cast<const void*>(&k_gemm2<1>),
                      hipFuncAttributeMaxDynamicSharedMemorySize, G2_LDS);

  k_gemm2<0><<<dim3(24, 32), dim3(512), G2_LDS, stream>>>(
      wqkvT, xb, bq, bk, bv, qw, kw, vtw, nullptr);

  k_attn<<<dim3(256), dim3(512), 0, stream>>>(qw, kw, vtw, att, 0);
  k_attn<<<dim3(256), dim3(512), 0, stream>>>(qw, kw, vtw, att, 4);

  k_gemm2<1><<<dim3(64, 4), dim3(512), G2_LDS, stream>>>(
      att, woT, bo, nullptr, nullptr, nullptr, nullptr, nullptr, out);
}

// Round 10
// 258.475 us; speedup vs baseline: 1.1190x; 1.1190x over previous
//
#include <hip/hip_runtime.h>
#include <stdint.h>

typedef float f32x4 __attribute__((ext_vector_type(4)));
typedef __bf16 bf16x8 __attribute__((ext_vector_type(8)));
typedef unsigned short ushort_t;
typedef ushort_t ushortx8 __attribute__((ext_vector_type(8)));
typedef ushort_t ushortx4 __attribute__((ext_vector_type(4)));

#define DEV static __device__ __forceinline__

DEV ushort_t f2bf(float f) {
  union { float f; uint32_t u; } v; v.f = f;
  uint32_t u = v.u;
  return (ushort_t)((u + 0x7FFFu + ((u >> 16) & 1u)) >> 16);
}

DEV uint32_t pkbf(float a, float b) {
  __bf16 x = (__bf16)a, y = (__bf16)b;
  return (uint32_t)__builtin_bit_cast(unsigned short, x) |
         ((uint32_t)__builtin_bit_cast(unsigned short, y) << 16);
}

DEV void cp16(const void* g, void* l) {
  __builtin_amdgcn_global_load_lds((const __attribute__((address_space(1))) unsigned int*)g,
                                   (__attribute__((address_space(3))) unsigned int*)l,
                                   16, 0, 0);
}

DEV f32x4 mfma16(bf16x8 a, bf16x8 b, f32x4 c) {
  return __builtin_amdgcn_mfma_f32_16x16x32_bf16(a, b, c, 0, 0, 0);
}

// ------------- merged prep: cvt x (blocks 0..4095), 4 weight transposes -----
__global__ __launch_bounds__(256) void k_prep(
    const float* __restrict__ x, ushort_t* __restrict__ xb,
    const float* __restrict__ wq, const float* __restrict__ wk,
    const float* __restrict__ wv, const float* __restrict__ wo,
    ushort_t* __restrict__ wqkvT, ushort_t* __restrict__ woT) {
  __shared__ float tile[32][33];
  int b = blockIdx.x;
  if (b < 4096) {
    size_t idx = ((size_t)b * 256 + threadIdx.x) * 8;
    const float4* src = (const float4*)(x + idx);
    float4 a = src[0], c = src[1];
    ushortx8 o;
    o[0] = f2bf(a.x); o[1] = f2bf(a.y); o[2] = f2bf(a.z); o[3] = f2bf(a.w);
    o[4] = f2bf(c.x); o[5] = f2bf(c.y); o[6] = f2bf(c.z); o[7] = f2bf(c.w);
    *(ushortx8*)(xb + idx) = o;
  } else {
    int t = b - 4096;
    int which = t >> 10;  // 0=wq 1=wk 2=wv 3=wo
    const float* src = (which == 0) ? wq : (which == 1) ? wk : (which == 2) ? wv : wo;
    ushort_t* dst = (which == 0) ? wqkvT
                    : (which == 1) ? wqkvT + 1024 * 1024
                    : (which == 2) ? wqkvT + 2 * 1024 * 1024
                                   : woT;
    int tt = t & 1023;
    int c0 = (tt & 31) * 32, r0 = (tt >> 5) * 32;
    int tx = threadIdx.x & 31, ty = threadIdx.x >> 5;
#pragma unroll
    for (int i = ty; i < 32; i += 8)
      tile[i][tx] = src[(size_t)(r0 + i) * 1024 + c0 + tx];
    __syncthreads();
#pragma unroll
    for (int i = ty; i < 32; i += 8)
      dst[(size_t)(c0 + i) * 1024 + r0 + tx] = f2bf(tile[tx][i]);
  }
}

// ------- unified GEMM: 128x256 tile, BK=64, 4-phase, 3-buf depth-2 ---------
// R9 counters: QKV = 71 us, MfmaUtil 29% -> depth-1 pipeline (vmcnt(2))
// exposes staging latency every tile. Fix: 3-buffer rotation (144 KiB LDS),
// tile t+2 staged 2-2-2 cp16 across phases 1-3 into buf (t+2)%3, single
// vmcnt(6) at phase 4 (FIFO: t+1's 6 loads landed; t+2's 6 stay in flight
// across the barrier). Buf (t+2)%3 was last read at tile t-1, whose reads
// completed before tile t began (per-phase barriers) -> race-free.
// 8 waves (2M x 4N), wave owns 64x64 = acc[4][4]; phase interleave as R6:
//   ph1 {rd a01+b01 | stg A(t+2)s0,s1 | bar lgk | MFMA a01xb01 | bar}
//   ph2 {rd b23     | stg B(t+2)s0,s1 | bar lgk | MFMA a01xb23 | bar}
//   ph3 {rd a23     | stg B(t+2)s2,s3 | bar lgk | MFMA a23xb23 | bar}
//   ph4 {vmcnt(6) | bar | MFMA a23xb01 (regs only) | bar}
// Tail: t2 clamped to NT-1 (dead re-stage into a rotation buf never read;
// stays within row bounds).
// MODE 0 (QKV): grid (24,32)=768 = 3 full rounds/CU; q/k scatter + V direct
//   transpose. MODE 1 (out proj): grid (64,4)=256 = 1/CU; fp32+bias.
template <int MODE>
__global__ __launch_bounds__(512, 1) void k_gemm2(
    const ushort_t* __restrict__ A, const ushort_t* __restrict__ Bt,
    const float* __restrict__ b0, const float* __restrict__ b1,
    const float* __restrict__ b2, ushort_t* __restrict__ qw,
    ushort_t* __restrict__ kw, ushort_t* __restrict__ vtw,
    float* __restrict__ outf) {
  extern __shared__ ushort_t lds[];
  ushort_t* As3 = lds;             // [3][128*64] = 48 KiB
  ushort_t* Bs3 = lds + 3 * 8192;  // [3][256*64] = 96 KiB
  const int K = 1024, NT = 16;
  int tid = threadIdx.x;
  int w = tid >> 6, lane = tid & 63, l16 = lane & 15, lg = lane >> 4;
  int wr = w >> 2, wc = w & 3;
  int m0 = blockIdx.x * 128, n0 = blockIdx.y * 256;

  const ushort_t* Asrc = A + (size_t)(m0 + (tid >> 3)) * K +
                         (size_t)(((tid & 7) ^ ((tid >> 3) & 7)) * 8);
  const ushort_t* Bsrc = Bt + (size_t)(n0 + (tid >> 3)) * K +
                         (size_t)(((tid & 7) ^ ((tid >> 3) & 7)) * 8);

  f32x4 acc[4][4] = {};
  bf16x8 a[2][2], b[4][2];
  const int aRow = wr * 64 + l16, bRow = wc * 64 + l16, rsw = l16 & 7;

  // prologue: stage tiles 0 (buf0) and 1 (buf1) fully; wait t0 (t1 in flight)
#pragma unroll
  for (int tt = 0; tt < 2; ++tt) {
    cp16(Asrc + (size_t)tt * 64, As3 + tt * 8192 + w * 512);
    cp16(Asrc + (size_t)tt * 64 + (size_t)64 * K, As3 + tt * 8192 + 4096 + w * 512);
#pragma unroll
    for (int s = 0; s < 4; ++s)
      cp16(Bsrc + (size_t)tt * 64 + (size_t)s * 64 * K,
           Bs3 + tt * 16384 + s * 4096 + w * 512);
  }
  asm volatile("s_waitcnt vmcnt(6)" ::: "memory");
  __builtin_amdgcn_s_barrier();

  int cur = 0, nx2 = 2;
  for (int t = 0; t < NT; ++t) {
    ushort_t* AsC = As3 + cur * 8192;
    ushort_t* BsC = Bs3 + cur * 16384;
    ushort_t* AsN = As3 + nx2 * 8192;
    ushort_t* BsN = Bs3 + nx2 * 16384;
    int t2 = (t + 2 < NT) ? t + 2 : NT - 1;
    const ushort_t* A2 = Asrc + (size_t)t2 * 64;
    const ushort_t* B2 = Bsrc + (size_t)t2 * 64;

    // ---- phase 1: read a0,a1 + b0,b1; stage A(t+2) s0,s1
#pragma unroll
    for (int i2 = 0; i2 < 2; ++i2)
#pragma unroll
      for (int ks = 0; ks < 2; ++ks)
        a[i2][ks] = *(const bf16x8*)&AsC[(aRow + i2 * 16) * 64 +
                                         (((ks << 2) | lg) ^ rsw) * 8];
#pragma unroll
    for (int j2 = 0; j2 < 2; ++j2)
#pragma unroll
      for (int ks = 0; ks < 2; ++ks)
        b[j2][ks] = *(const bf16x8*)&BsC[(bRow + j2 * 16) * 64 +
                                         (((ks << 2) | lg) ^ rsw) * 8];
    cp16(A2, AsN + w * 512);
    cp16(A2 + (size_t)64 * K, AsN + 4096 + w * 512);
    __builtin_amdgcn_s_barrier();
    asm volatile("s_waitcnt lgkmcnt(0)" ::: "memory");
    __builtin_amdgcn_s_setprio(1);
#pragma unroll
    for (int i2 = 0; i2 < 2; ++i2)
#pragma unroll
      for (int j2 = 0; j2 < 2; ++j2)
#pragma unroll
        for (int ks = 0; ks < 2; ++ks)
          acc[i2][j2] = mfma16(a[i2][ks], b[j2][ks], acc[i2][j2]);
    __builtin_amdgcn_s_setprio(0);
    __builtin_amdgcn_s_barrier();

    // ---- phase 2: read b2,b3; stage B(t+2) s0,s1
#pragma unroll
    for (int j2 = 2; j2 < 4; ++j2)
#pragma unroll
      for (int ks = 0; ks < 2; ++ks)
        b[j2][ks] = *(const bf16x8*)&BsC[(bRow + j2 * 16) * 64 +
                                         (((ks << 2) | lg) ^ rsw) * 8];
    cp16(B2, BsN + w * 512);
    cp16(B2 + (size_t)64 * K, BsN + 4096 + w * 512);
    __builtin_amdgcn_s_barrier();
    asm volatile("s_waitcnt lgkmcnt(0)" ::: "memory");
    __builtin_amdgcn_s_setprio(1);
#pragma unroll
    for (int i2 = 0; i2 < 2; ++i2)
#pragma unroll
      for (int j2 = 2; j2 < 4; ++j2)
#pragma unroll
        for (int ks = 0; ks < 2; ++ks)
          acc[i2][j2] = mfma16(a[i2][ks], b[j2][ks], acc[i2][j2]);
    __builtin_amdgcn_s_setprio(0);
    __builtin_amdgcn_s_barrier();

    // ---- phase 3: read a2,a3 (overwrite a[]); stage B(t+2) s2,s3
#pragma unroll
    for (int i2 = 0; i2 < 2; ++i2)
#pragma unroll
      for (int ks = 0; ks < 2; ++ks)
        a[i2][ks] = *(const bf16x8*)&AsC[(aRow + (2 + i2) * 16) * 64 +
                                         (((ks << 2) | lg) ^ rsw) * 8];
    cp16(B2 + (size_t)2 * 64 * K, BsN + 8192 + w * 512);
    cp16(B2 + (size_t)3 * 64 * K, BsN + 12288 + w * 512);
    __builtin_amdgcn_s_barrier();
    asm volatile("s_waitcnt lgkmcnt(0)" ::: "memory");
    __builtin_amdgcn_s_setprio(1);
#pragma unroll
    for (int i2 = 0; i2 < 2; ++i2)
#pragma unroll
      for (int j2 = 2; j2 < 4; ++j2)
#pragma unroll
        for (int ks = 0; ks < 2; ++ks)
          acc[2 + i2][j2] = mfma16(a[i2][ks], b[j2][ks], acc[2 + i2][j2]);
    __builtin_amdgcn_s_setprio(0);
    __builtin_amdgcn_s_barrier();

    // ---- phase 4: counted wait only — t+1 fully landed, t+2's 6 in flight
    asm volatile("s_waitcnt vmcnt(6)" ::: "memory");
    __builtin_amdgcn_s_barrier();
    __builtin_amdgcn_s_setprio(1);
#pragma unroll
    for (int i2 = 0; i2 < 2; ++i2)
#pragma unroll
      for (int j2 = 0; j2 < 2; ++j2)
#pragma unroll
        for (int ks = 0; ks < 2; ++ks)
          acc[2 + i2][j2] = mfma16(a[i2][ks], b[j2][ks], acc[2 + i2][j2]);
    __builtin_amdgcn_s_setprio(0);
    __builtin_amdgcn_s_barrier();

    cur = (cur + 1 == 3) ? 0 : cur + 1;
    nx2 = (nx2 + 1 == 3) ? 0 : nx2 + 1;
  }

  if (MODE == 0) {
    const float QSCALE = 0.18033688011112042f;  // (1/sqrt(64)) * log2(e)
    int p = blockIdx.x >> 3;  // 0=q 1=k 2=v
    int cbase = (m0 & 1023) + wr * 64;
    if (p == 2) {
      // V: write transposed directly -> vtw[bh][dh][token]
#pragma unroll
      for (int i = 0; i < 4; ++i) {
        int oc = cbase + i * 16 + lg * 4;
        int h = oc >> 6, dh0 = oc & 63;
        float4 bb = *(const float4*)&b2[oc];
#pragma unroll
        for (int j = 0; j < 4; ++j) {
          int tok = n0 + wc * 64 + j * 16 + l16;
          int bi = tok >> 11, tk = tok & 2047;
          size_t vb = ((size_t)((bi * 16 + h) * 64 + dh0)) * 2048 + tk;
          vtw[vb] = f2bf(acc[i][j][0] + bb.x);
          vtw[vb + 2048] = f2bf(acc[i][j][1] + bb.y);
          vtw[vb + 2 * 2048] = f2bf(acc[i][j][2] + bb.z);
          vtw[vb + 3 * 2048] = f2bf(acc[i][j][3] + bb.w);
        }
      }
    } else {
      const float* bias = (p == 0) ? b0 : b1;
      ushort_t* dst = (p == 0) ? qw : kw;
      float qs = (p == 0) ? QSCALE : 1.0f;
#pragma unroll
      for (int i = 0; i < 4; ++i) {
        int oc = cbase + i * 16 + lg * 4;
        int h = oc >> 6, dh0 = oc & 63;
        float4 bb = *(const float4*)&bias[oc];
#pragma unroll
        for (int j = 0; j < 4; ++j) {
          int tok = n0 + wc * 64 + j * 16 + l16;
          size_t base =
              ((size_t)((tok >> 11) * 16 + h) * 2048 + (tok & 2047)) * 64 + dh0;
          ushortx4 pk;
          pk[0] = f2bf((acc[i][j][0] + bb.x) * qs);
          pk[1] = f2bf((acc[i][j][1] + bb.y) * qs);
          pk[2] = f2bf((acc[i][j][2] + bb.z) * qs);
          pk[3] = f2bf((acc[i][j][3] + bb.w) * qs);
          *(ushortx4*)&dst[base] = pk;
        }
      }
    }
  } else {
    // fp32 + bias
#pragma unroll
    for (int j = 0; j < 4; ++j) {
      int col = n0 + wc * 64 + j * 16 + l16;
      float bb = b0[col];
#pragma unroll
      for (int i = 0; i < 4; ++i) {
#pragma unroll
        for (int r = 0; r < 4; ++r) {
          int row = m0 + wr * 64 + i * 16 + lg * 4 + r;
          outf[(size_t)row * 1024 + col] = acc[i][j][r] + bb;
        }
      }
    }
  }
}

// ---------------- flash attention, dbuf/KV64 version (control, ~82 us) -----
__global__ __launch_bounds__(512, 2) void k_attn(
    const ushort_t* __restrict__ qg, const ushort_t* __restrict__ kg,
    const ushort_t* __restrict__ vtg, ushort_t* __restrict__ att) {
  __shared__ ushort_t Ks[2][64 * 64];    // dbuf [key][dh], chunk8 ^= key&7
  __shared__ ushort_t Vs[2][64 * 64];    // dbuf [dh][key], chunk8 ^= dh&7
  __shared__ ushort_t Ps[8][16 * 128];   // per-wave [q][st*64+key], chunk16 ^= q
  int tid = threadIdx.x;
  int w = tid >> 6, lane = tid & 63, l16 = lane & 15, lg = lane >> 4;
  int i = blockIdx.x;
  int bh = (i & 7) * 8 + ((i >> 3) & 7);
  int q0 = (i >> 6) * 256;
  const ushort_t* qh = qg + (size_t)bh * 2048 * 64;

  const ushort_t* kstage = kg + (size_t)bh * 2048 * 64 + (size_t)(tid >> 3) * 64 +
                           (size_t)(((tid & 7) ^ ((tid >> 3) & 7)) * 8);
  const ushort_t* vstage = vtg + (size_t)bh * 64 * 2048 + (size_t)(tid >> 3) * 2048 +
                           (size_t)(((tid & 7) ^ ((tid >> 3) & 7)) * 8);

  bf16x8 qf[2][2];
#pragma unroll
  for (int st = 0; st < 2; ++st)
#pragma unroll
    for (int ks = 0; ks < 2; ++ks)
      qf[st][ks] = *(const bf16x8*)(qh + (size_t)(q0 + w * 32 + st * 16 + l16) * 64 +
                                    ks * 32 + lg * 8);

  bf16x8 vone;
#pragma unroll
  for (int t = 0; t < 8; ++t) vone[t] = (__bf16)1.0f;

  f32x4 o[2][5] = {};  // [strip][dh-tile 0..3, 4 = row-sum l]

  cp16(kstage, &Ks[0][tid * 8]);
  cp16(vstage, &Vs[0][tid * 8]);
  __syncthreads();

  for (int t = 0; t < 32; ++t) {
    int cur = t & 1, nxt = cur ^ 1;
    cp16(kstage + (size_t)(t + 1) * 64 * 64, &Ks[nxt][tid * 8]);
    cp16(vstage + (size_t)(t + 1) * 64, &Vs[nxt][tid * 8]);

    f32x4 sc[2][4] = {};
    __builtin_amdgcn_s_setprio(1);
#pragma unroll
    for (int jt = 0; jt < 4; ++jt) {
      int row = jt * 16 + l16;
      bf16x8 kf0 = *(const bf16x8*)&Ks[cur][row * 64 + ((lg) ^ (l16 & 7)) * 8];
      bf16x8 kf1 = *(const bf16x8*)&Ks[cur][row * 64 + ((lg + 4) ^ (l16 & 7)) * 8];
      sc[0][jt] = mfma16(kf0, qf[0][0], sc[0][jt]);
      sc[0][jt] = mfma16(kf1, qf[0][1], sc[0][jt]);
      sc[1][jt] = mfma16(kf0, qf[1][0], sc[1][jt]);
      sc[1][jt] = mfma16(kf1, qf[1][1], sc[1][jt]);
    }
    __builtin_amdgcn_s_setprio(0);

#pragma unroll
    for (int st = 0; st < 2; ++st)
#pragma unroll
      for (int jt = 0; jt < 4; ++jt) {
        float e0 = __builtin_amdgcn_exp2f(sc[st][jt][0]);
        float e1 = __builtin_amdgcn_exp2f(sc[st][jt][1]);
        float e2 = __builtin_amdgcn_exp2f(sc[st][jt][2]);
        float e3 = __builtin_amdgcn_exp2f(sc[st][jt][3]);
        uint2 pk2;
        pk2.x = pkbf(e0, e1);
        pk2.y = pkbf(e2, e3);
        *(uint2*)&Ps[w][l16 * 128 +
                        (((st * 8 + jt * 2 + (lg >> 1)) ^ l16) * 8) +
                        (lg & 1) * 4] = pk2;
      }

    __builtin_amdgcn_s_setprio(1);
#pragma unroll
    for (int ks = 0; ks < 2; ++ks) {
      bf16x8 pf0 =
          *(const bf16x8*)&Ps[w][l16 * 128 + (((ks * 4 + lg) ^ l16) * 8)];
      bf16x8 pf1 =
          *(const bf16x8*)&Ps[w][l16 * 128 + (((8 + ks * 4 + lg) ^ l16) * 8)];
      o[0][4] = mfma16(pf0, vone, o[0][4]);
      o[1][4] = mfma16(pf1, vone, o[1][4]);
#pragma unroll
      for (int dt = 0; dt < 4; ++dt) {
        int vrow = dt * 16 + l16;
        bf16x8 vf =
            *(const bf16x8*)&Vs[cur][vrow * 64 + (((ks * 4 + lg) ^ (l16 & 7)) * 8)];
        o[0][dt] = mfma16(pf0, vf, o[0][dt]);
        o[1][dt] = mfma16(pf1, vf, o[1][dt]);
      }
    }
    __builtin_amdgcn_s_setprio(0);

    __syncthreads();
  }

  int bi = bh >> 4, h = bh & 15;
#pragma unroll
  for (int st = 0; st < 2; ++st) {
    f32x4 inv;
#pragma unroll
    for (int r = 0; r < 4; ++r) inv[r] = __builtin_amdgcn_rcpf(o[st][4][r]);
#pragma unroll
    for (int dt = 0; dt < 4; ++dt)
#pragma unroll
      for (int r = 0; r < 4; ++r) {
        int srow = q0 + w * 32 + st * 16 + lg * 4 + r;
        int col = h * 64 + dt * 16 + l16;
        att[(size_t)(bi * 2048 + srow) * 1024 + col] = f2bf(o[st][dt][r] * inv[r]);
      }
  }
}

// ---------------- host ----------------
extern "C" void kernel_launch(void* const* d_in, const int* in_sizes, int n_in,
                              void* d_out, int out_size, void* d_ws, size_t ws_size,
                              hipStream_t stream) {
  const float* x = (const float*)d_in[0];
  const float* wq = (const float*)d_in[1];
  const float* bq = (const float*)d_in[2];
  const float* wk = (const float*)d_in[3];
  const float* bk = (const float*)d_in[4];
  const float* wv = (const float*)d_in[5];
  const float* bv = (const float*)d_in[6];
  const float* wo = (const float*)d_in[7];
  const float* bo = (const float*)d_in[8];
  float* out = (float*)d_out;

  char* ws = (char*)d_ws;
  ushort_t* xb = (ushort_t*)(ws);                       // 16 MiB
  ushort_t* wqkvT = (ushort_t*)(ws + 16777216);         // 6 MiB ([3072][1024])
  ushort_t* woT = (ushort_t*)(ws + 23068672);           // 2 MiB ([1024][1024])
  ushort_t* qw = (ushort_t*)(ws + 25165824);            // 16 MiB
  ushort_t* kw = (ushort_t*)(ws + 41943040);            // 16 MiB
  ushort_t* vtw = (ushort_t*)(ws + 58720256);           // 16 MiB
  ushort_t* att = (ushort_t*)(ws + 75497472);           // 16 MiB

  k_prep<<<dim3(8192), dim3(256), 0, stream>>>(x, xb, wq, wk, wv, wo, wqkvT, woT);

  const int G2_LDS = 147456;  // 144 KiB dynamic (3-buffer rotation)
  hipFuncSetAttribute(reinterpret_cast<const void*>(&k_gemm2<0>),
                      hipFuncAttributeMaxDynamicSharedMemorySize, G2_LDS);
  hipFuncSetAttribute(reinterpret_cast<const void*>(&k_gemm2<1>),
                      hipFuncAttributeMaxDynamicSharedMemorySize, G2_LDS);

  k_gemm2<0><<<dim3(24, 32), dim3(512), G2_LDS, stream>>>(
      wqkvT, xb, bq, bk, bv, qw, kw, vtw, nullptr);

  k_attn<<<dim3(512), dim3(512), 0, stream>>>(qw, kw, vtw, att);

  k_gemm2<1><<<dim3(64, 4), dim3(512), G2_LDS, stream>>>(
      att, woT, bo, nullptr, nullptr, nullptr, nullptr, nullptr, out);
}